// Round 1
// baseline (23.882 us; speedup 1.0000x reference)
//
#include <hip/hip_runtime.h>

#define BB 256
#define VV 10475
#define RR 75
#define KK 5
#define RKN (RR * KK)   // 375 gathered points
#define NOUT (RR * RR)  // 5625 entries per batch

__global__ __launch_bounds__(256) void ContactMap_47691316854895_kernel(
    const float* __restrict__ v1,
    const float* __restrict__ v2,
    const int* __restrict__ rid,
    float* __restrict__ out)
{
    __shared__ float g1s[RKN * 3];
    __shared__ float g2s[RKN * 3];

    const int b = blockIdx.x;
    const float* v1b = v1 + (size_t)b * VV * 3;
    const float* v2b = v2 + (size_t)b * VV * 3;

    // Cooperative gather of all 375 points for this batch into LDS.
    for (int t = threadIdx.x; t < RKN; t += blockDim.x) {
        const int idx = rid[t];
        const float* p1 = v1b + (size_t)idx * 3;
        const float* p2 = v2b + (size_t)idx * 3;
        g1s[t * 3 + 0] = p1[0];
        g1s[t * 3 + 1] = p1[1];
        g1s[t * 3 + 2] = p1[2];
        g2s[t * 3 + 0] = p2[0];
        g2s[t * 3 + 1] = p2[1];
        g2s[t * 3 + 2] = p2[2];
    }
    __syncthreads();

    const int e = blockIdx.y * blockDim.x + threadIdx.x;
    if (e >= NOUT) return;
    const int i = e / RR;   // residue index into g1
    const int j = e % RR;   // residue index into g2

    float best = 3.402823466e+38f;
#pragma unroll
    for (int p = 0; p < KK; ++p) {
        const float ax = g1s[(i * KK + p) * 3 + 0];
        const float ay = g1s[(i * KK + p) * 3 + 1];
        const float az = g1s[(i * KK + p) * 3 + 2];
#pragma unroll
        for (int q = 0; q < KK; ++q) {
            const float dx = ax - g2s[(j * KK + q) * 3 + 0];
            const float dy = ay - g2s[(j * KK + q) * 3 + 1];
            const float dz = az - g2s[(j * KK + q) * 3 + 2];
            const float d2 = dx * dx + dy * dy + dz * dz;
            best = fminf(best, d2);
        }
    }
    out[(size_t)b * NOUT + e] = sqrtf(best);
}

extern "C" void kernel_launch(void* const* d_in, const int* in_sizes, int n_in,
                              void* d_out, int out_size, void* d_ws, size_t ws_size,
                              hipStream_t stream) {
    const float* v1 = (const float*)d_in[0];
    const float* v2 = (const float*)d_in[1];
    const int* rid = (const int*)d_in[2];
    float* out = (float*)d_out;

    dim3 grid(BB, (NOUT + 255) / 256);
    dim3 block(256);
    ContactMap_47691316854895_kernel<<<grid, block, 0, stream>>>(v1, v2, rid, out);
}

// Round 2
// 15.148 us; speedup vs baseline: 1.5766x; 1.5766x over previous
//
#include <hip/hip_runtime.h>

#define BB 256
#define VV 10475
#define RR 75
#define KK 5
#define RKN (RR * KK)   // 375 gathered points
#define NOUT (RR * RR)  // 5625 entries per batch
#define TPB 1024

__global__ __launch_bounds__(TPB) void ContactMap_47691316854895_kernel(
    const float* __restrict__ v1,
    const float* __restrict__ v2,
    const int* __restrict__ rid,
    float* __restrict__ out)
{
    __shared__ float g1s[RKN * 3];
    __shared__ float g2s[RKN * 3];

    const int b = blockIdx.x;
    const float* v1b = v1 + (size_t)b * VV * 3;
    const float* v2b = v2 + (size_t)b * VV * 3;

    // One-pass gather of all 375 points for this batch into LDS.
    if (threadIdx.x < RKN) {
        const int t = threadIdx.x;
        const int idx = rid[t];
        const float* p1 = v1b + (size_t)idx * 3;
        const float* p2 = v2b + (size_t)idx * 3;
        g1s[t * 3 + 0] = p1[0];
        g1s[t * 3 + 1] = p1[1];
        g1s[t * 3 + 2] = p1[2];
        g2s[t * 3 + 0] = p2[0];
        g2s[t * 3 + 1] = p2[1];
        g2s[t * 3 + 2] = p2[2];
    }
    __syncthreads();

    float* outb = out + (size_t)b * NOUT;

    for (int e = threadIdx.x; e < NOUT; e += TPB) {
        const int i = e / RR;   // residue index into g1
        const int j = e % RR;   // residue index into g2

        // Hoist the 5 a-points into registers.
        float ax[KK], ay[KK], az[KK];
#pragma unroll
        for (int p = 0; p < KK; ++p) {
            ax[p] = g1s[(i * KK + p) * 3 + 0];
            ay[p] = g1s[(i * KK + p) * 3 + 1];
            az[p] = g1s[(i * KK + p) * 3 + 2];
        }

        float best = 3.402823466e+38f;
#pragma unroll
        for (int q = 0; q < KK; ++q) {
            const float bx = g2s[(j * KK + q) * 3 + 0];
            const float by = g2s[(j * KK + q) * 3 + 1];
            const float bz = g2s[(j * KK + q) * 3 + 2];
#pragma unroll
            for (int p = 0; p < KK; ++p) {
                const float dx = ax[p] - bx;
                const float dy = ay[p] - by;
                const float dz = az[p] - bz;
                const float d2 = dx * dx + dy * dy + dz * dz;
                best = fminf(best, d2);
            }
        }
        outb[e] = sqrtf(best);
    }
}

extern "C" void kernel_launch(void* const* d_in, const int* in_sizes, int n_in,
                              void* d_out, int out_size, void* d_ws, size_t ws_size,
                              hipStream_t stream) {
    const float* v1 = (const float*)d_in[0];
    const float* v2 = (const float*)d_in[1];
    const int* rid = (const int*)d_in[2];
    float* out = (float*)d_out;

    ContactMap_47691316854895_kernel<<<dim3(BB), dim3(TPB), 0, stream>>>(v1, v2, rid, out);
}

// Round 3
// 14.390 us; speedup vs baseline: 1.6596x; 1.0527x over previous
//
#include <hip/hip_runtime.h>
#include <float.h>

#define BB 256
#define VV 10475
#define RR 75
#define KK 5
#define RKN (RR * KK)    // 375 gathered points
#define NOUT (RR * RR)   // 5625 entries per batch
#define TI 3
#define TJ 3
#define NTI (RR / TI)    // 25
#define NTJ (RR / TJ)    // 25
#define NTILE (NTI * NTJ) // 625 active compute threads
#define TPB 640          // 10 waves

__global__ __launch_bounds__(TPB) void ContactMap_47691316854895_kernel(
    const float* __restrict__ v1,
    const float* __restrict__ v2,
    const int* __restrict__ rid,
    float* __restrict__ out)
{
    // Padded float4 points -> every LDS access is one ds_read_b128.
    __shared__ float4 g1s[RKN];
    __shared__ float4 g2s[RKN];

    const int b = blockIdx.x;
    const int tid = threadIdx.x;
    const float* v1b = v1 + (size_t)b * VV * 3;
    const float* v2b = v2 + (size_t)b * VV * 3;

    if (tid < RKN) {
        const int idx = rid[tid];
        const float* p1 = v1b + (size_t)idx * 3;
        const float* p2 = v2b + (size_t)idx * 3;
        g1s[tid] = make_float4(p1[0], p1[1], p1[2], 0.0f);
        g2s[tid] = make_float4(p2[0], p2[1], p2[2], 0.0f);
    }
    __syncthreads();

    if (tid >= NTILE) return;

    const int i0 = (tid / NTJ) * TI;
    const int j0 = (tid % NTJ) * TJ;

    // Hoist the 3 a-residues (15 points) into registers.
    float ax[TI][KK], ay[TI][KK], az[TI][KK];
#pragma unroll
    for (int ii = 0; ii < TI; ++ii) {
#pragma unroll
        for (int p = 0; p < KK; ++p) {
            const float4 a = g1s[(i0 + ii) * KK + p];
            ax[ii][p] = a.x; ay[ii][p] = a.y; az[ii][p] = a.z;
        }
    }

    float* outb = out + (size_t)b * NOUT;

#pragma unroll
    for (int jj = 0; jj < TJ; ++jj) {
        float bx[KK], by[KK], bz[KK];
#pragma unroll
        for (int q = 0; q < KK; ++q) {
            const float4 v = g2s[(j0 + jj) * KK + q];
            bx[q] = v.x; by[q] = v.y; bz[q] = v.z;
        }
#pragma unroll
        for (int ii = 0; ii < TI; ++ii) {
            float best = FLT_MAX;
#pragma unroll
            for (int p = 0; p < KK; ++p) {
#pragma unroll
                for (int q = 0; q < KK; ++q) {
                    const float dx = ax[ii][p] - bx[q];
                    const float dy = ay[ii][p] - by[q];
                    const float dz = az[ii][p] - bz[q];
                    const float d2 = dx * dx + dy * dy + dz * dz;
                    best = fminf(best, d2);
                }
            }
            outb[(size_t)(i0 + ii) * RR + (j0 + jj)] = sqrtf(best);
        }
    }
}

extern "C" void kernel_launch(void* const* d_in, const int* in_sizes, int n_in,
                              void* d_out, int out_size, void* d_ws, size_t ws_size,
                              hipStream_t stream) {
    const float* v1 = (const float*)d_in[0];
    const float* v2 = (const float*)d_in[1];
    const int* rid = (const int*)d_in[2];
    float* out = (float*)d_out;

    ContactMap_47691316854895_kernel<<<dim3(BB), dim3(TPB), 0, stream>>>(v1, v2, rid, out);
}